// Round 5
// baseline (957.917 us; speedup 1.0000x reference)
//
#include <hip/hip_runtime.h>
#include <hip/hip_bf16.h>
#include <stdint.h>

typedef unsigned short u16;
typedef __attribute__((ext_vector_type(8))) short short8;
typedef __attribute__((ext_vector_type(4))) float floatx4;

#define B_   512
#define D_   512
#define C_   100000

#define SCALE_  64.0f
#define COSM_   0.8775825618903728f
#define SINM_   0.479425538604203f
#define TH_     (-0.8775825618903728f)
#define MM_     0.2397127693021015f
#define EPS_    1e-7f
#define SHIFT_  89.6f

#define BM 256
#define BN 64
#define BK 32

// async global->LDS, 16 B per lane. lds_ptr MUST be wave-uniform; HW writes
// lane i at lds_ptr + i*16 (m104). Global src is per-lane (swizzle there).
#define GLDS16(gsrc, ldst) __builtin_amdgcn_global_load_lds(                 \
    (const __attribute__((address_space(1))) uint32_t*)(gsrc),               \
    (__attribute__((address_space(3))) uint32_t*)(ldst), 16, 0, 0)

__device__ inline float wave_reduce_sum(float v) {
    v += __shfl_xor(v, 1);
    v += __shfl_xor(v, 2);
    v += __shfl_xor(v, 4);
    v += __shfl_xor(v, 8);
    v += __shfl_xor(v, 16);
    v += __shfl_xor(v, 32);
    return v;
}

__device__ inline u16 f2bf(float x) {
    union { float f; uint32_t u; } v; v.f = x;
    uint32_t r = v.u + 0x7fffu + ((v.u >> 16) & 1u);  // RNE
    return (u16)(r >> 16);
}

// RNE pack of two fp32 -> one dword of 2x bf16 (v_cvt_pk_bf16_f32)
__device__ inline uint32_t cvt2_rn(float a, float b) {
    union { __hip_bfloat162 h; uint32_t u; } v;
    v.h = __float22bfloat162_rn(make_float2(a, b));
    return v.u;
}

// Fused: normalize embedding rows -> e_bf16, per-row phi (exact fp32 path),
// and zero-init rowsum (replaces a separate memset dispatch).
__global__ __launch_bounds__(256) void norm_e_phi_kernel(
    const float* __restrict__ emb, const float* __restrict__ w_raw,
    const int* __restrict__ gt, u16* __restrict__ e_bf16,
    float* __restrict__ phi, float* __restrict__ rowsum) {
    if (threadIdx.x < 4) rowsum[blockIdx.x * 4 + threadIdx.x] = 0.0f;
    int wv = threadIdx.x >> 6;
    int lane = threadIdx.x & 63;
    int b = blockIdx.x * 4 + wv;
    const float4* rp = (const float4*)(emb + (long)b * D_);
    float4 f0 = rp[lane], f1 = rp[lane + 64];
    float sq = f0.x*f0.x + f0.y*f0.y + f0.z*f0.z + f0.w*f0.w
             + f1.x*f1.x + f1.y*f1.y + f1.z*f1.z + f1.w*f1.w;
    sq = wave_reduce_sum(sq);
    float rn = 1.0f / sqrtf(sq);
    f0.x *= rn; f0.y *= rn; f0.z *= rn; f0.w *= rn;
    f1.x *= rn; f1.y *= rn; f1.z *= rn; f1.w *= rn;
    uint2 p0, p1;
    p0.x = (uint32_t)f2bf(f0.x) | ((uint32_t)f2bf(f0.y) << 16);
    p0.y = (uint32_t)f2bf(f0.z) | ((uint32_t)f2bf(f0.w) << 16);
    p1.x = (uint32_t)f2bf(f1.x) | ((uint32_t)f2bf(f1.y) << 16);
    p1.y = (uint32_t)f2bf(f1.z) | ((uint32_t)f2bf(f1.w) << 16);
    uint2* ob = (uint2*)(e_bf16 + (long)b * D_);
    ob[lane] = p0;
    ob[lane + 64] = p1;

    int g = gt[b];
    const float4* wp = (const float4*)(w_raw + (long)g * D_);
    float4 w0 = wp[lane], w1 = wp[lane + 64];
    float dt = f0.x*w0.x + f0.y*w0.y + f0.z*w0.z + f0.w*w0.w
             + f1.x*w1.x + f1.y*w1.y + f1.z*w1.z + f1.w*w1.w;
    float wsq = w0.x*w0.x + w0.y*w0.y + w0.z*w0.z + w0.w*w0.w
              + w1.x*w1.x + w1.y*w1.y + w1.z*w1.z + w1.w*w1.w;
    dt = wave_reduce_sum(dt);
    wsq = wave_reduce_sum(wsq);
    if (lane == 0) {
        float pos = dt / sqrtf(wsq);
        pos = fminf(fmaxf(pos, -1.0f + EPS_), 1.0f - EPS_);
        float s2 = 1.0f - pos * pos;
        s2 = fminf(fmaxf(s2, EPS_), 1.0f - EPS_);
        float sin_t = sqrtf(s2);
        float ph = pos * COSM_ - sin_t * SINM_;
        ph = (pos > TH_) ? ph : (pos - MM_);
        phi[b] = ph;
    }
}

// GEMM with CORRECT global_load_lds staging (m97 pattern):
//  - per wave per K-step: 2 GLDS16 with WAVE-UNIFORM lds base (btile +
//    (2wv+j)*1024B); HW writes lane i at base+16i -> lane-linear 1KB.
//    (Round 3 passed a per-lane lds_ptr -> illegal lowering, 772MB scratch.)
//  - W stays fp32 in LDS (2x8KB dbuf). Swizzle on SOURCE side: phys 16B
//    slot p of row R holds logical slot p^(R&7); read side applies the
//    same XOR -> each 16B slot hit by exactly 8 lanes (uniform coverage,
//    same class as the layout measured at 0 conflicts in r0).
//  - fp32->bf16 cvt_pk after the ds_read_b128; column sumsq in-register
//    (thread covers k 8q..8q+7 of rows ni*16+low4; shfl_xor 16|32 closes).
//  - loads no longer transit VGPRs -> in-flight depth decoupled from
//    register budget (the r0/r4 structural cap: 4 loads/wave, drained at
//    every barrier, MfmaUtil 8.5%).
//  - bijective XCD swizzle puts both M-halves of a c-tile on one XCD
//    (shared 128KB W-tile becomes an L2 hit instead of L3).
__global__ __launch_bounds__(256, 3) void gemm_arcface_fused(
    const u16* __restrict__ a_g,     // e_bf16 [512][512]
    const float* __restrict__ w_g,   // raw weight fp32 [100000][512]
    const float* __restrict__ phi, const int* __restrict__ gt,
    float* __restrict__ rowsum) {
    __shared__ __align__(16) float btile[2][BN * BK];  // 2 x 8 KB fp32
    __shared__ float phi_s[BM];
    __shared__ int gt_s[BM];

    int tid = threadIdx.x;
    // XCD swizzle, pair-major: 3126 blocks = 8*390+6 -> q=390, r=6.
    // Blocks on one XCD get consecutive virtual ids = consecutive pairs.
    int bid = blockIdx.x;
    int x = bid & 7;
    int v = (x < 6 ? x * 391 : 6 * 391 + (x - 6) * 390) + (bid >> 3);
    int c0 = (v >> 1) * BN;
    int m0 = (v & 1) * BM;

    phi_s[tid] = phi[m0 + tid];
    gt_s[tid] = gt[m0 + tid];

    int wv = tid >> 6, lane = tid & 63;
    int low4 = lane & 15, quad = lane >> 4;

    // --- staging setup (per-lane GLOBAL addr, wave-uniform LDS base) ---
    // call j covers rows wv*16 + 8j + (lane>>3); R&7 == lane>>3 for both.
    int R0 = wv * 16 + (lane >> 3);
    int sw = ((lane & 7) ^ (lane >> 3)) * 4;   // pre-swizzled float offset
    long gr0 = min(c0 + R0,     C_ - 1);
    long gr1 = min(c0 + R0 + 8, C_ - 1);
    const float* gsrc0 = w_g + gr0 * D_ + sw;
    const float* gsrc1 = w_g + gr1 * D_ + sw;
    float* ld0[2] = { &btile[0][wv * 512],       &btile[1][wv * 512] };
    float* ld1[2] = { &btile[0][wv * 512 + 256], &btile[1][wv * 512 + 256] };

    // --- fragment read setup ---
    const u16* a_base = a_g + (long)(m0 + wv * 64 + low4) * D_ + quad * 8;
    // phys 16B unit of logical unit 2q for row r: (2q)^(r&7); hi = ^1.
    int p0f = ((quad * 2) ^ (low4 & 7)) * 4;   // float offset within row
    int rowoff[4];
#pragma unroll
    for (int ni = 0; ni < 4; ni++) rowoff[ni] = (ni * 16 + low4) * BK;

    // prologue: stage tile 0 into buf 0
    GLDS16(gsrc0, ld0[0]);
    GLDS16(gsrc1, ld1[0]);
    __syncthreads();   // drains prologue stage + phi_s/gt_s

    floatx4 acc[4][4] = {};
    float sq[4] = {0.0f, 0.0f, 0.0f, 0.0f};

#pragma unroll
    for (int kt = 0; kt < 16; kt++) {
        const float* btc = btile[kt & 1];
        if (kt < 15) {   // stage kt+1 into the other buffer (async, in LDS)
            int nb = (kt + 1) & 1;
            GLDS16(gsrc0 + (kt + 1) * BK, ld0[nb]);
            GLDS16(gsrc1 + (kt + 1) * BK, ld1[nb]);
        }
        short8 af[4];
#pragma unroll
        for (int mi = 0; mi < 4; mi++)
            af[mi] = *(const short8*)(a_base + (long)mi * 16 * D_ + kt * BK);
#pragma unroll
        for (int ni = 0; ni < 4; ni++) {
            float4 lo = *(const float4*)(btc + rowoff[ni] + p0f);
            float4 hi = *(const float4*)(btc + rowoff[ni] + (p0f ^ 4));
            sq[ni] += lo.x*lo.x + lo.y*lo.y + lo.z*lo.z + lo.w*lo.w
                    + hi.x*hi.x + hi.y*hi.y + hi.z*hi.z + hi.w*hi.w;
            union { short8 s; uint32_t u[4]; } bb;
            bb.u[0] = cvt2_rn(lo.x, lo.y);
            bb.u[1] = cvt2_rn(lo.z, lo.w);
            bb.u[2] = cvt2_rn(hi.x, hi.y);
            bb.u[3] = cvt2_rn(hi.z, hi.w);
#pragma unroll
            for (int mi = 0; mi < 4; mi++)
                acc[mi][ni] = __builtin_amdgcn_mfma_f32_16x16x32_bf16(
                    af[mi], bb.s, acc[mi][ni], 0, 0, 0);
        }
        __syncthreads();   // vmcnt(0)+lgkmcnt(0): kt+1 staged, kt reads done
    }

    // per-column 1/||w||: thread holds k-slice 8q..8q+7 of rows ni*16+low4
    float rnorm[4];
#pragma unroll
    for (int ni = 0; ni < 4; ni++) {
        float s = sq[ni];
        s += __shfl_xor(s, 16);
        s += __shfl_xor(s, 32);
        rnorm[ni] = 1.0f / sqrtf(s);
    }

    // epilogue: normalize, clip, reweight, gt-substitute, exp, row-reduce
#pragma unroll
    for (int mi = 0; mi < 4; mi++) {
#pragma unroll
        for (int r = 0; r < 4; r++) {
            int rl = wv * 64 + mi * 16 + quad * 4 + r;
            float ph = phi_s[rl];
            int g = gt_s[rl];
            float s = 0.0f;
#pragma unroll
            for (int ni = 0; ni < 4; ni++) {
                int cl = ni * 16 + low4;
                int c = c0 + cl;
                float vv = acc[mi][ni][r] * rnorm[ni];
                vv = fminf(fmaxf(vv, -1.0f + EPS_), 1.0f - EPS_);
                float logit = (vv > ph) ? (1.2f * vv + 0.2f) : vv;
                logit *= SCALE_;
                if (c == g) logit = SCALE_ * ph;
                s += (c < C_) ? __expf(logit - SHIFT_) : 0.0f;
            }
            s += __shfl_xor(s, 1);
            s += __shfl_xor(s, 2);
            s += __shfl_xor(s, 4);
            s += __shfl_xor(s, 8);
            if (low4 == 0) atomicAdd(&rowsum[m0 + rl], s);
        }
    }
}

__global__ __launch_bounds__(256) void loss_kernel(
    const float* __restrict__ rowsum, const float* __restrict__ phi,
    float* __restrict__ out) {
    __shared__ float red[4];
    int tid = threadIdx.x;
    float s = 0.0f;
    for (int b = tid; b < B_; b += 256)
        s += logf(rowsum[b]) + SHIFT_ - SCALE_ * phi[b];
    s = wave_reduce_sum(s);
    int wv = tid >> 6, lane = tid & 63;
    if (lane == 0) red[wv] = s;
    __syncthreads();
    if (tid == 0) out[0] = (red[0] + red[1] + red[2] + red[3]) * (1.0f / B_);
}

extern "C" void kernel_launch(void* const* d_in, const int* in_sizes, int n_in,
                              void* d_out, int out_size, void* d_ws, size_t ws_size,
                              hipStream_t stream) {
    const float* emb = (const float*)d_in[0];   // [512][512] f32
    const float* wgt = (const float*)d_in[1];   // [100000][512] f32
    const int* gt = (const int*)d_in[2];        // [512] int32
    float* out = (float*)d_out;

    char* ws = (char*)d_ws;
    u16* e_bf16 = (u16*)(ws);                   //   524,288 B
    float* phi = (float*)(ws + 524288);         //     2,048 B
    float* rowsum = (float*)(ws + 526336);      //     2,048 B

    norm_e_phi_kernel<<<B_ / 4, 256, 0, stream>>>(emb, wgt, gt, e_bf16, phi, rowsum);
    int nc = (C_ + BN - 1) / BN;                // 1563 c-tiles
    gemm_arcface_fused<<<nc * 2, 256, 0, stream>>>(e_bf16, wgt, phi, gt, rowsum);
    loss_kernel<<<1, 256, 0, stream>>>(rowsum, phi, out);
}

// Round 6
// 444.909 us; speedup vs baseline: 2.1531x; 2.1531x over previous
//
#include <hip/hip_runtime.h>
#include <hip/hip_bf16.h>
#include <stdint.h>

typedef unsigned short u16;
typedef __attribute__((ext_vector_type(8))) short short8;
typedef __attribute__((ext_vector_type(4))) float floatx4;

#define B_   512
#define D_   512
#define C_   100000

#define SCALE_  64.0f
#define COSM_   0.8775825618903728f
#define SINM_   0.479425538604203f
#define TH_     (-0.8775825618903728f)
#define MM_     0.2397127693021015f
#define EPS_    1e-7f
#define SHIFT_  89.6f

#define BM 256
#define BN 64
#define BK 32

__device__ inline float wave_reduce_sum(float v) {
    v += __shfl_xor(v, 1);
    v += __shfl_xor(v, 2);
    v += __shfl_xor(v, 4);
    v += __shfl_xor(v, 8);
    v += __shfl_xor(v, 16);
    v += __shfl_xor(v, 32);
    return v;
}

__device__ inline u16 f2bf(float x) {
    union { float f; uint32_t u; } v; v.f = x;
    uint32_t r = v.u + 0x7fffu + ((v.u >> 16) & 1u);  // RNE
    return (u16)(r >> 16);
}

// Fused: normalize embedding rows -> e_bf16, per-row phi (exact fp32 path),
// and zero-init rowsum (replaces a separate memset dispatch).
__global__ __launch_bounds__(256) void norm_e_phi_kernel(
    const float* __restrict__ emb, const float* __restrict__ w_raw,
    const int* __restrict__ gt, u16* __restrict__ e_bf16,
    float* __restrict__ phi, float* __restrict__ rowsum) {
    if (threadIdx.x < 4) rowsum[blockIdx.x * 4 + threadIdx.x] = 0.0f;
    int wv = threadIdx.x >> 6;
    int lane = threadIdx.x & 63;
    int b = blockIdx.x * 4 + wv;
    const float4* rp = (const float4*)(emb + (long)b * D_);
    float4 f0 = rp[lane], f1 = rp[lane + 64];
    float sq = f0.x*f0.x + f0.y*f0.y + f0.z*f0.z + f0.w*f0.w
             + f1.x*f1.x + f1.y*f1.y + f1.z*f1.z + f1.w*f1.w;
    sq = wave_reduce_sum(sq);
    float rn = 1.0f / sqrtf(sq);
    f0.x *= rn; f0.y *= rn; f0.z *= rn; f0.w *= rn;
    f1.x *= rn; f1.y *= rn; f1.z *= rn; f1.w *= rn;
    uint2 p0, p1;
    p0.x = (uint32_t)f2bf(f0.x) | ((uint32_t)f2bf(f0.y) << 16);
    p0.y = (uint32_t)f2bf(f0.z) | ((uint32_t)f2bf(f0.w) << 16);
    p1.x = (uint32_t)f2bf(f1.x) | ((uint32_t)f2bf(f1.y) << 16);
    p1.y = (uint32_t)f2bf(f1.z) | ((uint32_t)f2bf(f1.w) << 16);
    uint2* ob = (uint2*)(e_bf16 + (long)b * D_);
    ob[lane] = p0;
    ob[lane + 64] = p1;

    int g = gt[b];
    const float4* wp = (const float4*)(w_raw + (long)g * D_);
    float4 w0 = wp[lane], w1 = wp[lane + 64];
    float dt = f0.x*w0.x + f0.y*w0.y + f0.z*w0.z + f0.w*w0.w
             + f1.x*w1.x + f1.y*w1.y + f1.z*w1.z + f1.w*w1.w;
    float wsq = w0.x*w0.x + w0.y*w0.y + w0.z*w0.z + w0.w*w0.w
              + w1.x*w1.x + w1.y*w1.y + w1.z*w1.z + w1.w*w1.w;
    dt = wave_reduce_sum(dt);
    wsq = wave_reduce_sum(wsq);
    if (lane == 0) {
        float pos = dt / sqrtf(wsq);
        pos = fminf(fmaxf(pos, -1.0f + EPS_), 1.0f - EPS_);
        float s2 = 1.0f - pos * pos;
        s2 = fminf(fmaxf(s2, EPS_), 1.0f - EPS_);
        float sin_t = sqrtf(s2);
        float ph = pos * COSM_ - sin_t * SINM_;
        ph = (pos > TH_) ? ph : (pos - MM_);
        phi[b] = ph;
    }
}

__device__ inline void cvt_store(const float4& v0, const float4& v1,
                                 u16* dst, float& sq) {
    union { u16 h[8]; uint4 q; } u;
    u.h[0] = f2bf(v0.x); u.h[1] = f2bf(v0.y);
    u.h[2] = f2bf(v0.z); u.h[3] = f2bf(v0.w);
    u.h[4] = f2bf(v1.x); u.h[5] = f2bf(v1.y);
    u.h[6] = f2bf(v1.z); u.h[7] = f2bf(v1.w);
    *(uint4*)dst = u.q;
    sq += v0.x*v0.x + v0.y*v0.y + v0.z*v0.z + v0.w*v0.w
        + v1.x*v1.x + v1.y*v1.y + v1.z*v1.z + v1.w*v1.w;
}

// GEMM over raw fp32 W with inline normalization + ArcFace + exp row-sums.
// r4 structure (reg-staged LDS dbuf, 0-conflict swizzle, lgkm-only barrier)
// with the bv register pipeline deepened 2 -> 4 stages. Diagnosis: r0==r4
// (drain removal changed nothing) proves the binder is prefetch DEPTH --
// bv issued at kt was consumed at kt+1 (~250cyc slack) vs ~600-900cyc
// L2/HBM latency, stalling every K-step (MfmaUtil 8.5%). Now tile kt+4 is
// issued at step kt and consumed (cvt_store) at kt+3: ~750cyc of slack
// spanning three barriers. Cost: +16 VGPR (bv[4][2]); still 3 blocks/CU.
__global__ __launch_bounds__(256, 3) void gemm_arcface_fused(
    const u16* __restrict__ a_g,     // e_bf16 [512][512]
    const float* __restrict__ w_g,   // raw weight fp32 [100000][512]
    const float* __restrict__ phi, const int* __restrict__ gt,
    float* __restrict__ rowsum) {
    __shared__ __align__(16) u16 b_tile[2][BN * BK];  // 2 x 4 KB
    __shared__ float phi_s[BM];
    __shared__ int gt_s[BM];
    __shared__ float rnorm_s[BN];

    int tid = threadIdx.x;
    int c0 = (blockIdx.x >> 1) * BN;
    int m0 = (blockIdx.x & 1) * BM;

    phi_s[tid] = phi[m0 + tid];
    gt_s[tid] = gt[m0 + tid];

    // B staging: thread t -> row rb=t>>2, LDS k-slot bslot=t&3, XOR-swizzled
    // global k-quad (bank-conflict-free, verified 0 conflicts).
    int rb = tid >> 2;
    int bslot = tid & 3;
    int bkq = bslot ^ ((rb >> 1) & 3);
    long brow_g = min(c0 + rb, C_ - 1);
    const float4* b_src = (const float4*)(w_g + brow_g * (long)D_ + bkq * 8);
    u16* b_dst0 = &b_tile[0][rb * BK + bslot * 8];
    u16* b_dst1 = &b_tile[1][rb * BK + bslot * 8];

    int wv = tid >> 6, lane = tid & 63;
    int low4 = lane & 15, quad = lane >> 4;
    int lslot = quad ^ ((low4 >> 1) & 3);
    const u16* a_base = a_g + (long)(m0 + wv * 64 + low4) * D_ + quad * 8;
    int bf_off = low4 * BK + lslot * 8;

    floatx4 acc[4][4] = {};
    float sq = 0.0f;
    float4 bv[4][2];     // 4-deep B register pipeline: bv[j] holds tile t, t%4==j
    short8 afc[4];

    // prologue: tiles 0..3 in flight; tile 0 converted into LDS buf 0
#pragma unroll
    for (int j = 0; j < 4; j++) {
        bv[j][0] = b_src[j * 8];
        bv[j][1] = b_src[j * 8 + 1];
    }
    cvt_store(bv[0][0], bv[0][1], b_dst0, sq);   // waits bv[0] only (counted)
    asm volatile("s_waitcnt lgkmcnt(0)" ::: "memory");
    __builtin_amdgcn_s_barrier();

#pragma unroll
    for (int kt = 0; kt < 16; kt++) {
        int p = kt & 1;
        // issue tile kt+4 into the slot freed when tile kt was converted
        // (cvt_store'd at step kt-1); consumed at step kt+3 -> 3-step slack
        if (kt < 12) {
            bv[kt & 3][0] = b_src[(kt + 4) * 8];
            bv[kt & 3][1] = b_src[(kt + 4) * 8 + 1];
        }
        // A fragments for this k-tile (L1/L2-warm)
#pragma unroll
        for (int mi = 0; mi < 4; mi++)
            afc[mi] = *(const short8*)(a_base + (long)mi * 16 * D_ + kt * BK);
        short8 bf[4];
#pragma unroll
        for (int ni = 0; ni < 4; ni++)
            bf[ni] = *(const short8*)(&b_tile[p][ni * 16 * BK + bf_off]);
#pragma unroll
        for (int mi = 0; mi < 4; mi++)
#pragma unroll
            for (int ni = 0; ni < 4; ni++)
                acc[mi][ni] = __builtin_amdgcn_mfma_f32_16x16x32_bf16(
                    afc[mi], bf[ni], acc[mi][ni], 0, 0, 0);
        // convert tile kt+1 (loaded 3 steps ago) into the other LDS buffer
        if (kt < 15)
            cvt_store(bv[(kt + 1) & 3][0], bv[(kt + 1) & 3][1],
                      p ? b_dst0 : b_dst1, sq);
        // barrier without vmcnt drain: only LDS ordering required
        asm volatile("s_waitcnt lgkmcnt(0)" ::: "memory");
        __builtin_amdgcn_s_barrier();
    }

    // per-column 1/||w||: the 4 staging threads of a row hold disjoint slices
    sq += __shfl_xor(sq, 1);
    sq += __shfl_xor(sq, 2);
    if ((tid & 3) == 0) rnorm_s[rb] = 1.0f / sqrtf(sq);
    __syncthreads();   // outside hot loop

    // epilogue: normalize, clip, reweight, gt-substitute, exp, row-reduce
#pragma unroll
    for (int mi = 0; mi < 4; mi++) {
#pragma unroll
        for (int r = 0; r < 4; r++) {
            int rl = wv * 64 + mi * 16 + quad * 4 + r;
            float ph = phi_s[rl];
            int g = gt_s[rl];
            float s = 0.0f;
#pragma unroll
            for (int ni = 0; ni < 4; ni++) {
                int cl = ni * 16 + low4;
                int c = c0 + cl;
                float v = acc[mi][ni][r] * rnorm_s[cl];
                v = fminf(fmaxf(v, -1.0f + EPS_), 1.0f - EPS_);
                float logit = (v > ph) ? (1.2f * v + 0.2f) : v;
                logit *= SCALE_;
                if (c == g) logit = SCALE_ * ph;
                s += (c < C_) ? __expf(logit - SHIFT_) : 0.0f;
            }
            s += __shfl_xor(s, 1);
            s += __shfl_xor(s, 2);
            s += __shfl_xor(s, 4);
            s += __shfl_xor(s, 8);
            if (low4 == 0) atomicAdd(&rowsum[m0 + rl], s);
        }
    }
}

__global__ __launch_bounds__(256) void loss_kernel(
    const float* __restrict__ rowsum, const float* __restrict__ phi,
    float* __restrict__ out) {
    __shared__ float red[4];
    int tid = threadIdx.x;
    float s = 0.0f;
    for (int b = tid; b < B_; b += 256)
        s += logf(rowsum[b]) + SHIFT_ - SCALE_ * phi[b];
    s = wave_reduce_sum(s);
    int wv = tid >> 6, lane = tid & 63;
    if (lane == 0) red[wv] = s;
    __syncthreads();
    if (tid == 0) out[0] = (red[0] + red[1] + red[2] + red[3]) * (1.0f / B_);
}

extern "C" void kernel_launch(void* const* d_in, const int* in_sizes, int n_in,
                              void* d_out, int out_size, void* d_ws, size_t ws_size,
                              hipStream_t stream) {
    const float* emb = (const float*)d_in[0];   // [512][512] f32
    const float* wgt = (const float*)d_in[1];   // [100000][512] f32
    const int* gt = (const int*)d_in[2];        // [512] int32
    float* out = (float*)d_out;

    char* ws = (char*)d_ws;
    u16* e_bf16 = (u16*)(ws);                   //   524,288 B
    float* phi = (float*)(ws + 524288);         //     2,048 B
    float* rowsum = (float*)(ws + 526336);      //     2,048 B

    norm_e_phi_kernel<<<B_ / 4, 256, 0, stream>>>(emb, wgt, gt, e_bf16, phi, rowsum);
    int nc = (C_ + BN - 1) / BN;                // 1563 c-tiles
    gemm_arcface_fused<<<nc * 2, 256, 0, stream>>>(e_bf16, wgt, phi, gt, rowsum);
    loss_kernel<<<1, 256, 0, stream>>>(rowsum, phi, out);
}